// Round 17
// baseline (239.015 us; speedup 1.0000x reference)
//
#include <hip/hip_runtime.h>
#include <hip/hip_cooperative_groups.h>
#include <math.h>

namespace cg = cooperative_groups;

#define B 8
#define S 512
#define D 512
#define H 8
#define DH 64
#define VOCAB (2 * (S - 1) + 1)   // 1023
#define GK 512
// r16: coop launch silently failed (absmax = zeros signature; unchecked return,
// likely co-residency too-large at 512 blocks). r17: grid-stride phases +
// occupancy query + checked fallback to the verified r14 4-kernel path.

typedef unsigned short u16;
typedef __attribute__((ext_vector_type(8))) short s16x8;
typedef __attribute__((ext_vector_type(4))) float f32x4;

__device__ __forceinline__ u16 f2bf(float f) {
    union { float f; unsigned u; } a; a.f = f;
    unsigned r = a.u + 0x7FFF + ((a.u >> 16) & 1);
    return (u16)(r >> 16);
}
__device__ __forceinline__ float bf2f(u16 h) {
    union { unsigned u; float f; } a; a.u = ((unsigned)h) << 16;
    return a.f;
}
__device__ __forceinline__ void cvt8(const float* __restrict__ s, u16* __restrict__ d) {
    float4 a = *(const float4*)s;
    float4 b = *(const float4*)(s + 4);
    s16x8 o;
    o[0] = f2bf(a.x); o[1] = f2bf(a.y); o[2] = f2bf(a.z); o[3] = f2bf(a.w);
    o[4] = f2bf(b.x); o[5] = f2bf(b.y); o[6] = f2bf(b.z); o[7] = f2bf(b.w);
    *(s16x8*)d = o;
}

#define GLOAD16(gp, lp) __builtin_amdgcn_global_load_lds( \
    (const __attribute__((address_space(1))) unsigned int*)(gp), \
    (__attribute__((address_space(3))) unsigned int*)(lp), 16, 0, 0)

// ---------------------------------------------------------------------------
// prep body (device fn, grid-stride with given stride) — r14-verified logic.
// ---------------------------------------------------------------------------
__device__ __forceinline__ void prep_body(
    const float* pos_emb, const float* q, const float* k, const float* v,
    const float* Wq, const float* Wk, const float* Wv, const float* Wr, const float* Wo,
    u16* pe_b, u16* qb, u16* kb, u16* vb,
    u16* Wqb, u16* Wkb, u16* Wvb, u16* Wrb, u16* Wob,
    int start, int stride)
{
    const int NPE8 = (1024 * 512) / 8;
    const int NW8  = (512 * 512) / 8;
    const int NBS8 = (B * S * D) / 8;
    const int total = NPE8 + 5 * NW8 + 3 * NBS8;
    for (int i = start; i < total; i += stride) {
        if (i < NPE8) {
            int e = i * 8;
            int row = e >> 9, col = e & 511;
            if (row >= VOCAB) {
                *(s16x8*)&pe_b[e] = (s16x8)(short)0;
            } else {
                int qq = (row < S) ? (S - 1) : 0;
                int kk = (row < S) ? row : (row - (S - 1));
                cvt8(&pos_emb[(qq * S + kk) * D + col], &pe_b[e]);
            }
            continue;
        }
        int j = i - NPE8;
        if (j < 5 * NW8) {
            int wi = j >> 15;
            int e = (j & (NW8 - 1)) * 8;
            const float* src; u16* dst;
            if      (wi == 0) { src = Wq; dst = Wqb; }
            else if (wi == 1) { src = Wk; dst = Wkb; }
            else if (wi == 2) { src = Wv; dst = Wvb; }
            else if (wi == 3) { src = Wr; dst = Wrb; }
            else              { src = Wo; dst = Wob; }
            cvt8(&src[e], &dst[e]);
            continue;
        }
        int j2 = j - 5 * NW8;
        int qi = j2 >> 18;
        int e = (j2 & (NBS8 - 1)) * 8;
        const float* src; u16* dst;
        if      (qi == 0) { src = q; dst = qb; }
        else if (qi == 1) { src = k; dst = kb; }
        else              { src = v; dst = vb; }
        cvt8(&src[e], &dst[e]);
    }
}

// ---------------------------------------------------------------------------
// 128x128-tile bf16 MFMA GEMM body (r14-verified: gload + both-sides XOR).
// ---------------------------------------------------------------------------
template<bool F32OUT>
__device__ __forceinline__ void gemm128_body(
    const u16* __restrict__ A, const u16* __restrict__ W,
    const float* __restrict__ bias, const float* __restrict__ resid,
    u16* __restrict__ Cb, float* __restrict__ Cf,
    int m0, int n0, u16* As, u16* Ws)
{
    int tid = threadIdx.x;
    int w = tid >> 6, lane = tid & 63;
    int wr = w >> 1, wc = w & 1;
    int lr = lane & 15, lk = lane >> 4;
    int c16 = ((lane & 7) ^ (lane >> 3)) * 8;
    int swz = (lr & 7) * 8;
    f32x4 acc[4][4] = {};

    for (int k0 = 0; k0 < GK; k0 += 64) {
        #pragma unroll
        for (int l = 0; l < 4; ++l) {
            int chunk = w * 4 + l;
            int r = chunk * 8 + (lane >> 3);
            GLOAD16(&A[(m0 + r) * GK + k0 + c16], &As[chunk * 512]);
            GLOAD16(&W[(n0 + r) * GK + k0 + c16], &Ws[chunk * 512]);
        }
        __syncthreads();
        #pragma unroll
        for (int ks = 0; ks < 2; ++ks) {
            s16x8 fa[4], fb[4];
            #pragma unroll
            for (int f = 0; f < 4; ++f) {
                fa[f] = *(const s16x8*)&As[(wr * 64 + f * 16 + lr) * 64 + ((ks * 32 + lk * 8) ^ swz)];
                fb[f] = *(const s16x8*)&Ws[(wc * 64 + f * 16 + lr) * 64 + ((ks * 32 + lk * 8) ^ swz)];
            }
            #pragma unroll
            for (int fm = 0; fm < 4; ++fm)
                #pragma unroll
                for (int fn = 0; fn < 4; ++fn)
                    acc[fm][fn] = __builtin_amdgcn_mfma_f32_16x16x32_bf16(
                        fa[fm], fb[fn], acc[fm][fn], 0, 0, 0);
        }
        __syncthreads();
    }
    #pragma unroll
    for (int fm = 0; fm < 4; ++fm) {
        #pragma unroll
        for (int r = 0; r < 4; ++r) {
            int m = m0 + wr * 64 + fm * 16 + lk * 4 + r;
            #pragma unroll
            for (int fn = 0; fn < 4; ++fn) {
                int n = n0 + wc * 64 + fn * 16 + lr;
                float vv = acc[fm][fn][r] + bias[n];
                if (F32OUT) Cf[m * 512 + n] = vv + resid[m * 512 + n];
                else        Cb[m * 512 + n] = f2bf(vv);
            }
        }
    }
}

// ---------------------------------------------------------------------------
// attn tile body (one (b,h,q0) tile) — r14-verified logic.
// ---------------------------------------------------------------------------
__device__ __forceinline__ void attn_body(
    const u16* qh, const u16* kh, const u16* vh, const u16* rproj,
    const float* u_bias, const float* v_bias, u16* ao,
    int bh, int q0, u16* K_s, u16* R_s, u16 (*Vt_s)[72], u16 (*TP_s)[16][88])
{
    int b = bh >> 3, h = bh & 7;
    int tid = threadIdx.x, w = tid >> 6, lane = tid & 63;
    int lr = lane & 15, lk = lane >> 4;
    int woff = 48 - 16 * w;
    int swz = (lr & 7) * 8;
    int c16 = ((lane & 7) ^ (lane >> 3)) * 8;

    s16x8 qu[2], qv[2];
    {
        int qrow = q0 + 16 * w + lr;
        const u16* qp = &qh[((b * S + qrow) * H + h) * DH];
        #pragma unroll
        for (int f = 0; f < 2; ++f) {
            int d0 = lk * 8 + f * 32;
            s16x8 qraw = *(const s16x8*)&qp[d0];
            s16x8 xu, xv;
            #pragma unroll
            for (int j = 0; j < 8; ++j) {
                float qf = bf2f((u16)qraw[j]);
                xu[j] = (short)f2bf((qf + u_bias[h * DH + d0 + j]) * 0.125f);
                xv[j] = (short)f2bf((qf + v_bias[h * DH + d0 + j]) * 0.125f);
            }
            qu[f] = xu; qv[f] = xv;
        }
    }

    float l_part[4] = {0.f, 0.f, 0.f, 0.f};
    f32x4 opv[4] = {};

    for (int kt = 0; kt < 8; ++kt) {
        int k0 = kt * 64;
        int rbase = k0 - q0 + 448;

        #pragma unroll
        for (int l = 0; l < 2; ++l) {
            int chunk = w * 2 + l;
            int r = chunk * 8 + (lane >> 3);
            GLOAD16(&kh[((b * S + k0 + r) * H + h) * DH + c16], &K_s[chunk * 512]);
        }
        #pragma unroll
        for (int l = 0; l < 4; ++l) {
            int chunk = w * 4 + l;
            int jr = chunk * 8 + (lane >> 3);
            int rr = rbase + jr; if (rr > 1022) rr = 1022;
            GLOAD16(&rproj[rr * D + h * DH + c16], &R_s[chunk * 512]);
        }
        {
            int kk2 = (tid & 31) * 2;
            int n8  = (tid >> 5) * 8;
            const u16* vp = &vh[((b * S + k0 + kk2) * H + h) * DH + n8];
            s16x8 v0 = *(const s16x8*)vp;
            s16x8 v1 = *(const s16x8*)(vp + H * DH);
            #pragma unroll
            for (int e = 0; e < 8; ++e) {
                ushort2 pr; pr.x = (u16)v0[e]; pr.y = (u16)v1[e];
                *(ushort2*)&Vt_s[n8 + e][kk2] = pr;
            }
        }
        __syncthreads();

        f32x4 sacc[4] = {};
        #pragma unroll
        for (int ks = 0; ks < 2; ++ks) {
            s16x8 bfr[4];
            #pragma unroll
            for (int cf = 0; cf < 4; ++cf)
                bfr[cf] = *(const s16x8*)&K_s[(cf * 16 + lr) * 64 + ((ks * 32 + lk * 8) ^ swz)];
            #pragma unroll
            for (int cf = 0; cf < 4; ++cf)
                sacc[cf] = __builtin_amdgcn_mfma_f32_16x16x32_bf16(
                    qu[ks], bfr[cf], sacc[cf], 0, 0, 0);
        }
        f32x4 tacc[5] = {};
        #pragma unroll
        for (int ks = 0; ks < 2; ++ks) {
            #pragma unroll
            for (int cf = 0; cf < 5; ++cf) {
                s16x8 bfr = *(const s16x8*)&R_s[(woff + cf * 16 + lr) * 64 + ((ks * 32 + lk * 8) ^ swz)];
                tacc[cf] = __builtin_amdgcn_mfma_f32_16x16x32_bf16(
                    qv[ks], bfr, tacc[cf], 0, 0, 0);
            }
        }
        #pragma unroll
        for (int cf = 0; cf < 5; ++cf)
            #pragma unroll
            for (int r = 0; r < 4; ++r)
                TP_s[w][lk * 4 + r][cf * 16 + lr] = f2bf(tacc[cf][r]);
        asm volatile("s_waitcnt lgkmcnt(0)" ::: "memory");

        #pragma unroll
        for (int cf = 0; cf < 4; ++cf)
            #pragma unroll
            for (int r = 0; r < 4; ++r) {
                int ql = lk * 4 + r, kk = lr + cf * 16;
                float p = __expf(sacc[cf][r] + bf2f(TP_s[w][ql][kk - ql + 15]));
                l_part[r] += p;
                TP_s[w][ql][kk] = f2bf(p);
            }
        asm volatile("s_waitcnt lgkmcnt(0)" ::: "memory");

        #pragma unroll
        for (int ks = 0; ks < 2; ++ks) {
            s16x8 pa = *(const s16x8*)&TP_s[w][lr][ks * 32 + lk * 8];
            #pragma unroll
            for (int cf = 0; cf < 4; ++cf) {
                s16x8 vf = *(const s16x8*)&Vt_s[cf * 16 + lr][ks * 32 + lk * 8];
                opv[cf] = __builtin_amdgcn_mfma_f32_16x16x32_bf16(
                    pa, vf, opv[cf], 0, 0, 0);
            }
        }
        __syncthreads();
    }

    #pragma unroll
    for (int mask = 1; mask < 16; mask <<= 1)
        #pragma unroll
        for (int r = 0; r < 4; ++r)
            l_part[r] += __shfl_xor(l_part[r], mask, 64);

    #pragma unroll
    for (int cf = 0; cf < 4; ++cf)
        #pragma unroll
        for (int r = 0; r < 4; ++r) {
            int qrow = q0 + 16 * w + lk * 4 + r;
            ao[((b * S + qrow) * H + h) * DH + lr + 16 * cf] =
                f2bf(opv[cf][r] / l_part[r]);
        }
}

__device__ __forceinline__ void ln_body(
    float* out, const float* g, const float* bta, int row, int lane)
{
    float vals[8];
    float sum = 0.f;
    #pragma unroll
    for (int j = 0; j < 8; ++j) {
        vals[j] = out[row * D + lane + j * 64];
        sum += vals[j];
    }
    #pragma unroll
    for (int off = 32; off; off >>= 1) sum += __shfl_xor(sum, off, 64);
    float mu = sum / (float)D;
    float sq = 0.f;
    #pragma unroll
    for (int j = 0; j < 8; ++j) { float dv = vals[j] - mu; sq += dv * dv; }
    #pragma unroll
    for (int off = 32; off; off >>= 1) sq += __shfl_xor(sq, off, 64);
    float rstd = rsqrtf(sq / (float)D + 1e-5f);
    #pragma unroll
    for (int j = 0; j < 8; ++j) {
        int c = lane + j * 64;
        out[row * D + c] = (vals[j] - mu) * rstd * g[c] + bta[c];
    }
}

union SMem {
    struct { u16 As[128 * 64]; u16 Ws[128 * 64]; } g;    // 32 KB
    struct { u16 K[64 * 64]; u16 R[128 * 64]; u16 Vt[64][72];
             u16 TP[4][16][88]; } a;                      // 44 KB
};

// ---------------------------------------------------------------------------
// Cooperative megakernel: 5 grid-stride phases, 4 grid.sync().
// ---------------------------------------------------------------------------
__global__ __launch_bounds__(256, 2) void mega(
    const float* __restrict__ q, const float* __restrict__ k, const float* __restrict__ v,
    const float* __restrict__ pos_emb,
    const float* __restrict__ Wq, const float* __restrict__ bq,
    const float* __restrict__ Wk, const float* __restrict__ bk,
    const float* __restrict__ Wv, const float* __restrict__ bv,
    const float* __restrict__ Wr, const float* __restrict__ br,
    const float* __restrict__ Wo, const float* __restrict__ bo,
    const float* __restrict__ u_bias, const float* __restrict__ v_bias,
    const float* __restrict__ ln_g, const float* __restrict__ ln_b,
    float* __restrict__ out, u16* __restrict__ ws)
{
    cg::grid_group grid = cg::this_grid();
    __shared__ SMem sm;

    const int NBS = B * S * D;
    const int NW  = D * D;
    const int NPE = 1024 * 512;
    u16* pe_b  = ws;
    u16* qb    = pe_b + NPE;
    u16* kb    = qb + NBS;
    u16* vb    = kb + NBS;
    u16* Wqb   = vb + NBS;
    u16* Wkb   = Wqb + NW;
    u16* Wvb   = Wkb + NW;
    u16* Wrb   = Wvb + NW;
    u16* Wob   = Wrb + NW;
    u16* rproj = Wob + NW;
    u16* qhb   = rproj + NPE;
    u16* khb   = qhb + NBS;
    u16* vhb   = khb + NBS;
    u16* aob   = vhb + NBS;

    int bid = blockIdx.x, tid = threadIdx.x;
    int nb = gridDim.x;

    // phase 1: prep
    prep_body(pos_emb, q, k, v, Wq, Wk, Wv, Wr, Wo,
              pe_b, qb, kb, vb, Wqb, Wkb, Wvb, Wrb, Wob,
              bid * 256 + tid, nb * 256);
    grid.sync();

    // phase 2: QKV + R projections (416 tiles, grid-stride)
    for (int t = bid; t < 416; t += nb) {
        const u16 *A, *W; const float* bias; u16* C;
        int by, bx;
        if (t < 384) {
            int z = t >> 7, rem = t & 127;
            by = rem >> 2; bx = rem & 3;
            if      (z == 0) { A = qb; W = Wqb; bias = bq; C = qhb; }
            else if (z == 1) { A = kb; W = Wkb; bias = bk; C = khb; }
            else             { A = vb; W = Wvb; bias = bv; C = vhb; }
        } else {
            int rem = t - 384;
            by = rem >> 2; bx = rem & 3;
            A = pe_b; W = Wrb; bias = br; C = rproj;
        }
        gemm128_body<false>(A, W, bias, nullptr, C, nullptr,
                            by * 128, bx * 128, sm.g.As, sm.g.Ws);
        __syncthreads();
    }
    grid.sync();

    // phase 3: attention (512 tiles, grid-stride)
    for (int t = bid; t < 512; t += nb) {
        attn_body(qhb, khb, vhb, rproj, u_bias, v_bias, aob,
                  t & 63, (t >> 6) * 64, sm.a.K, sm.a.R, sm.a.Vt, sm.a.TP);
        __syncthreads();
    }
    grid.sync();

    // phase 4: out-proj + residual (128 tiles, grid-stride)
    for (int t = bid; t < 128; t += nb) {
        gemm128_body<true>(aob, Wob, bo, q, nullptr, out,
                           (t >> 2) * 128, (t & 3) * 128, sm.g.As, sm.g.Ws);
        __syncthreads();
    }
    grid.sync();

    // phase 5: LayerNorm (1024 logical blocks of 4 rows)
    {
        int w = tid >> 6, lane = tid & 63;
        for (int lb = bid; lb < (B * S) / 4; lb += nb)
            ln_body(out, ln_g, ln_b, lb * 4 + w, lane);
    }
}

// ---------------------------------------------------------------------------
// Fallback kernels (r14-verified path).
// ---------------------------------------------------------------------------
__global__ __launch_bounds__(256) void prep_k(
    const float* pos_emb, const float* q, const float* k, const float* v,
    const float* Wq, const float* Wk, const float* Wv, const float* Wr, const float* Wo,
    u16* pe_b, u16* qb, u16* kb, u16* vb,
    u16* Wqb, u16* Wkb, u16* Wvb, u16* Wrb, u16* Wob)
{
    prep_body(pos_emb, q, k, v, Wq, Wk, Wv, Wr, Wo,
              pe_b, qb, kb, vb, Wqb, Wkb, Wvb, Wrb, Wob,
              blockIdx.x * 256 + threadIdx.x, gridDim.x * 256);
}

__global__ __launch_bounds__(256) void proj_qkvr_k(
    const u16* qb, const u16* kb, const u16* vb, const u16* pe_b,
    const u16* Wqb, const u16* Wkb, const u16* Wvb, const u16* Wrb,
    const float* bq, const float* bk, const float* bv, const float* br,
    u16* qhb, u16* khb, u16* vhb, u16* rproj)
{
    __shared__ u16 As[128 * 64];
    __shared__ u16 Ws[128 * 64];
    const u16 *A, *W; const float* bias; u16* C;
    int z = blockIdx.z;
    if      (z == 0) { A = qb;   W = Wqb; bias = bq; C = qhb; }
    else if (z == 1) { A = kb;   W = Wkb; bias = bk; C = khb; }
    else if (z == 2) { A = vb;   W = Wvb; bias = bv; C = vhb; }
    else             { A = pe_b; W = Wrb; bias = br; C = rproj;
                       if (blockIdx.y >= 8) return; }
    gemm128_body<false>(A, W, bias, nullptr, C, nullptr,
                        blockIdx.y * 128, blockIdx.x * 128, As, Ws);
}

__global__ __launch_bounds__(256) void proj_out_k(
    const u16* aob, const u16* Wob, const float* bo, const float* resid, float* out)
{
    __shared__ u16 As[128 * 64];
    __shared__ u16 Ws[128 * 64];
    gemm128_body<true>(aob, Wob, bo, resid, nullptr, out,
                       blockIdx.y * 128, blockIdx.x * 128, As, Ws);
}

__global__ __launch_bounds__(256, 2) void attn_k(
    const u16* qh, const u16* kh, const u16* vh, const u16* rproj,
    const float* u_bias, const float* v_bias, u16* ao)
{
    __shared__ u16 K_s[64 * 64];
    __shared__ u16 R_s[128 * 64];
    __shared__ u16 Vt_s[64][72];
    __shared__ u16 TP_s[4][16][88];
    attn_body(qh, kh, vh, rproj, u_bias, v_bias, ao,
              blockIdx.x, blockIdx.y * 64, K_s, R_s, Vt_s, TP_s);
}

__global__ __launch_bounds__(256) void ln_k(
    float* out, const float* g, const float* bta)
{
    ln_body(out, g, bta, blockIdx.x * 4 + threadIdx.x / 64, threadIdx.x % 64);
}

// ---------------------------------------------------------------------------
extern "C" void kernel_launch(void* const* d_in, const int* in_sizes, int n_in,
                              void* d_out, int out_size, void* d_ws, size_t ws_size,
                              hipStream_t stream) {
    const float* q       = (const float*)d_in[0];
    const float* k       = (const float*)d_in[1];
    const float* v       = (const float*)d_in[2];
    const float* pos_emb = (const float*)d_in[3];
    const float* Wq = (const float*)d_in[4];  const float* bq = (const float*)d_in[5];
    const float* Wk = (const float*)d_in[6];  const float* bk = (const float*)d_in[7];
    const float* Wv = (const float*)d_in[8];  const float* bv = (const float*)d_in[9];
    const float* Wr = (const float*)d_in[10]; const float* br = (const float*)d_in[11];
    const float* Wo = (const float*)d_in[12]; const float* bo = (const float*)d_in[13];
    const float* u_bias = (const float*)d_in[14];
    const float* v_bias = (const float*)d_in[15];
    const float* ln_g = (const float*)d_in[16];
    const float* ln_b = (const float*)d_in[17];
    float* out = (float*)d_out;
    u16* wsp = (u16*)d_ws;

    const int NBS = B * S * D;
    const int NW  = D * D;
    const int NPE = 1024 * 512;
    u16* pe_b  = wsp;
    u16* qb    = pe_b + NPE;
    u16* kb    = qb + NBS;
    u16* vb    = kb + NBS;
    u16* Wqb   = vb + NBS;
    u16* Wkb   = Wqb + NW;
    u16* Wvb   = Wkb + NW;
    u16* Wrb   = Wvb + NW;
    u16* Wob   = Wrb + NW;
    u16* rproj = Wob + NW;
    u16* qhb   = rproj + NPE;
    u16* khb   = qhb + NBS;
    u16* vhb   = khb + NBS;
    u16* aob   = vhb + NBS;

    // cooperative path: size grid to guaranteed co-residency
    int maxPerCU = 0;
    hipError_t qerr = hipOccupancyMaxActiveBlocksPerMultiprocessor(
        &maxPerCU, mega, 256, 0);
    bool coop_ok = (qerr == hipSuccess && maxPerCU >= 1);
    if (coop_ok) {
        int nblk = (maxPerCU >= 2) ? 512 : 256;
        void* args[] = {
            (void*)&q, (void*)&k, (void*)&v, (void*)&pos_emb,
            (void*)&Wq, (void*)&bq, (void*)&Wk, (void*)&bk,
            (void*)&Wv, (void*)&bv, (void*)&Wr, (void*)&br,
            (void*)&Wo, (void*)&bo, (void*)&u_bias, (void*)&v_bias,
            (void*)&ln_g, (void*)&ln_b, (void*)&out, (void*)&wsp
        };
        hipError_t lerr = hipLaunchCooperativeKernel(
            (const void*)mega, dim3(nblk), dim3(256), args, 0, stream);
        if (lerr == hipSuccess) return;
    }

    // fallback: r14-verified 4-kernel path
    dim3 blk(256);
    prep_k<<<2048, blk, 0, stream>>>(pos_emb, q, k, v, Wq, Wk, Wv, Wr, Wo,
                                     pe_b, qb, kb, vb, Wqb, Wkb, Wvb, Wrb, Wob);
    proj_qkvr_k<<<dim3(4, 32, 4), blk, 0, stream>>>(
        qb, kb, vb, pe_b, Wqb, Wkb, Wvb, Wrb, bq, bk, bv, br,
        qhb, khb, vhb, rproj);
    attn_k<<<dim3(B * H, S / 64), blk, 0, stream>>>(qhb, khb, vhb, rproj,
                                                    u_bias, v_bias, aob);
    proj_out_k<<<dim3(4, 32), blk, 0, stream>>>(aob, Wob, bo, q, out);
    ln_k<<<B * S / 4, blk, 0, stream>>>(out, ln_g, ln_b);
}

// Round 18
// 111.776 us; speedup vs baseline: 2.1383x; 2.1383x over previous
//
#include <hip/hip_runtime.h>
#include <math.h>

#define B 8
#define S 512
#define D 512
#define H 8
#define DH 64
#define VOCAB (2 * (S - 1) + 1)   // 1023
#define GK 512
// r16/r17: cooperative megafusion = grid.sync costs ~60us+ on 8-XCD (L2
// writeback per sync) -> abandoned. r18 = r14 (80us best) with LN fused into
// proj_out via per-stripe completion counters (atomic+threadfence, G12/G16).

typedef unsigned short u16;
typedef __attribute__((ext_vector_type(8))) short s16x8;
typedef __attribute__((ext_vector_type(4))) float f32x4;

__device__ __forceinline__ u16 f2bf(float f) {
    union { float f; unsigned u; } a; a.f = f;
    unsigned r = a.u + 0x7FFF + ((a.u >> 16) & 1);
    return (u16)(r >> 16);
}
__device__ __forceinline__ float bf2f(u16 h) {
    union { unsigned u; float f; } a; a.u = ((unsigned)h) << 16;
    return a.f;
}
__device__ __forceinline__ void cvt8(const float* __restrict__ s, u16* __restrict__ d) {
    float4 a = *(const float4*)s;
    float4 b = *(const float4*)(s + 4);
    s16x8 o;
    o[0] = f2bf(a.x); o[1] = f2bf(a.y); o[2] = f2bf(a.z); o[3] = f2bf(a.w);
    o[4] = f2bf(b.x); o[5] = f2bf(b.y); o[6] = f2bf(b.z); o[7] = f2bf(b.w);
    *(s16x8*)d = o;
}

#define GLOAD16(gp, lp) __builtin_amdgcn_global_load_lds( \
    (const __attribute__((address_space(1))) unsigned int*)(gp), \
    (__attribute__((address_space(3))) unsigned int*)(lp), 16, 0, 0)

// ---------------------------------------------------------------------------
// Fused prep (r6-verified) + zeroing of the 32 stripe counters.
// ---------------------------------------------------------------------------
__global__ __launch_bounds__(256) void prep(
    const float* __restrict__ pos_emb,
    const float* __restrict__ q, const float* __restrict__ k, const float* __restrict__ v,
    const float* __restrict__ Wq, const float* __restrict__ Wk, const float* __restrict__ Wv,
    const float* __restrict__ Wr, const float* __restrict__ Wo,
    u16* __restrict__ pe_b, u16* __restrict__ qb, u16* __restrict__ kb, u16* __restrict__ vb,
    u16* __restrict__ Wqb, u16* __restrict__ Wkb, u16* __restrict__ Wvb,
    u16* __restrict__ Wrb, u16* __restrict__ Wob, int* __restrict__ ctr)
{
    if (blockIdx.x == 0 && threadIdx.x < 32) ctr[threadIdx.x] = 0;

    const int NPE8 = (1024 * 512) / 8;
    const int NW8  = (512 * 512) / 8;
    const int NBS8 = (B * S * D) / 8;
    const int total = NPE8 + 5 * NW8 + 3 * NBS8;
    for (int i = blockIdx.x * 256 + threadIdx.x; i < total; i += gridDim.x * 256) {
        if (i < NPE8) {
            int e = i * 8;
            int row = e >> 9, col = e & 511;
            if (row >= VOCAB) {
                *(s16x8*)&pe_b[e] = (s16x8)(short)0;
            } else {
                int qq = (row < S) ? (S - 1) : 0;
                int kk = (row < S) ? row : (row - (S - 1));
                cvt8(&pos_emb[(qq * S + kk) * D + col], &pe_b[e]);
            }
            continue;
        }
        int j = i - NPE8;
        if (j < 5 * NW8) {
            int wi = j >> 15;
            int e = (j & (NW8 - 1)) * 8;
            const float* src; u16* dst;
            if      (wi == 0) { src = Wq; dst = Wqb; }
            else if (wi == 1) { src = Wk; dst = Wkb; }
            else if (wi == 2) { src = Wv; dst = Wvb; }
            else if (wi == 3) { src = Wr; dst = Wrb; }
            else              { src = Wo; dst = Wob; }
            cvt8(&src[e], &dst[e]);
            continue;
        }
        int j2 = j - 5 * NW8;
        int qi = j2 >> 18;
        int e = (j2 & (NBS8 - 1)) * 8;
        const float* src; u16* dst;
        if      (qi == 0) { src = q; dst = qb; }
        else if (qi == 1) { src = k; dst = kb; }
        else              { src = v; dst = vb; }
        cvt8(&src[e], &dst[e]);
    }
}

// ---------------------------------------------------------------------------
// 128x128-tile bf16 MFMA GEMM body (r14-verified: gload + both-sides XOR).
// ---------------------------------------------------------------------------
template<bool F32OUT>
__device__ __forceinline__ void gemm128_body(
    const u16* __restrict__ A, const u16* __restrict__ W,
    const float* __restrict__ bias, const float* __restrict__ resid,
    u16* __restrict__ Cb, float* __restrict__ Cf,
    int m0, int n0, u16* As, u16* Ws)
{
    int tid = threadIdx.x;
    int w = tid >> 6, lane = tid & 63;
    int wr = w >> 1, wc = w & 1;
    int lr = lane & 15, lk = lane >> 4;
    int c16 = ((lane & 7) ^ (lane >> 3)) * 8;
    int swz = (lr & 7) * 8;
    f32x4 acc[4][4] = {};

    for (int k0 = 0; k0 < GK; k0 += 64) {
        #pragma unroll
        for (int l = 0; l < 4; ++l) {
            int chunk = w * 4 + l;
            int r = chunk * 8 + (lane >> 3);
            GLOAD16(&A[(m0 + r) * GK + k0 + c16], &As[chunk * 512]);
            GLOAD16(&W[(n0 + r) * GK + k0 + c16], &Ws[chunk * 512]);
        }
        __syncthreads();
        #pragma unroll
        for (int ks = 0; ks < 2; ++ks) {
            s16x8 fa[4], fb[4];
            #pragma unroll
            for (int f = 0; f < 4; ++f) {
                fa[f] = *(const s16x8*)&As[(wr * 64 + f * 16 + lr) * 64 + ((ks * 32 + lk * 8) ^ swz)];
                fb[f] = *(const s16x8*)&Ws[(wc * 64 + f * 16 + lr) * 64 + ((ks * 32 + lk * 8) ^ swz)];
            }
            #pragma unroll
            for (int fm = 0; fm < 4; ++fm)
                #pragma unroll
                for (int fn = 0; fn < 4; ++fn)
                    acc[fm][fn] = __builtin_amdgcn_mfma_f32_16x16x32_bf16(
                        fa[fm], fb[fn], acc[fm][fn], 0, 0, 0);
        }
        __syncthreads();
    }
    #pragma unroll
    for (int fm = 0; fm < 4; ++fm) {
        #pragma unroll
        for (int r = 0; r < 4; ++r) {
            int m = m0 + wr * 64 + fm * 16 + lk * 4 + r;
            #pragma unroll
            for (int fn = 0; fn < 4; ++fn) {
                int n = n0 + wc * 64 + fn * 16 + lr;
                float vv = acc[fm][fn][r] + bias[n];
                if (F32OUT) Cf[m * 512 + n] = vv + resid[m * 512 + n];
                else        Cb[m * 512 + n] = f2bf(vv);
            }
        }
    }
}

__global__ __launch_bounds__(256) void proj_qkvr(
    const u16* __restrict__ qb, const u16* __restrict__ kb, const u16* __restrict__ vb,
    const u16* __restrict__ pe_b,
    const u16* __restrict__ Wqb, const u16* __restrict__ Wkb, const u16* __restrict__ Wvb,
    const u16* __restrict__ Wrb,
    const float* __restrict__ bq, const float* __restrict__ bk, const float* __restrict__ bv,
    const float* __restrict__ br,
    u16* __restrict__ qhb, u16* __restrict__ khb, u16* __restrict__ vhb,
    u16* __restrict__ rproj)
{
    __shared__ u16 As[128 * 64];
    __shared__ u16 Ws[128 * 64];
    const u16 *A, *W; const float* bias; u16* C;
    int z = blockIdx.z;
    if      (z == 0) { A = qb;   W = Wqb; bias = bq; C = qhb; }
    else if (z == 1) { A = kb;   W = Wkb; bias = bk; C = khb; }
    else if (z == 2) { A = vb;   W = Wvb; bias = bv; C = vhb; }
    else             { A = pe_b; W = Wrb; bias = br; C = rproj;
                       if (blockIdx.y >= 8) return; }   // pe: M=1024
    gemm128_body<false>(A, W, bias, nullptr, C, nullptr,
                        blockIdx.y * 128, blockIdx.x * 128, As, Ws);
}

// ---------------------------------------------------------------------------
// Output projection + residual + FUSED LayerNorm.
// 4 column-blocks per 128-row stripe; last finisher (atomic ctr) LNs the stripe.
// ---------------------------------------------------------------------------
__global__ __launch_bounds__(256) void proj_out_ln(
    const u16* __restrict__ aob, const u16* __restrict__ Wob,
    const float* __restrict__ bo, const float* __restrict__ resid,
    float* __restrict__ out,
    const float* __restrict__ ln_g, const float* __restrict__ ln_b,
    int* __restrict__ ctr)
{
    __shared__ u16 As[128 * 64];
    __shared__ u16 Ws[128 * 64];
    __shared__ int flag;
    int by = blockIdx.y;

    gemm128_body<true>(aob, Wob, bo, resid, nullptr, out,
                       by * 128, blockIdx.x * 128, As, Ws);
    __syncthreads();

    if (threadIdx.x == 0) {
        __threadfence();                       // release our tile stores
        flag = atomicAdd(&ctr[by], 1);
    }
    __syncthreads();
    if (flag != 3) return;                     // not the last of 4 col-blocks
    __threadfence();                           // acquire others' stores

    int w = threadIdx.x >> 6, lane = threadIdx.x & 63;
    for (int r0 = w; r0 < 128; r0 += 4) {
        int row = by * 128 + r0;
        float vals[8];
        float sum = 0.f;
        #pragma unroll
        for (int j = 0; j < 8; ++j) {
            vals[j] = out[row * D + lane + j * 64];
            sum += vals[j];
        }
        #pragma unroll
        for (int off = 32; off; off >>= 1) sum += __shfl_xor(sum, off, 64);
        float mu = sum / (float)D;
        float sq = 0.f;
        #pragma unroll
        for (int j = 0; j < 8; ++j) { float dv = vals[j] - mu; sq += dv * dv; }
        #pragma unroll
        for (int off = 32; off; off >>= 1) sq += __shfl_xor(sq, off, 64);
        float rstd = rsqrtf(sq / (float)D + 1e-5f);
        #pragma unroll
        for (int j = 0; j < 8; ++j) {
            int c = lane + j * 64;
            out[row * D + c] = (vals[j] - mu) * rstd * ln_g[c] + ln_b[c];
        }
    }
}

// ---------------------------------------------------------------------------
// Fused relative attention — r10/r14-verified structure.
// ---------------------------------------------------------------------------
__global__ __launch_bounds__(256, 2) void attn_mfma(
    const u16* __restrict__ qh, const u16* __restrict__ kh,
    const u16* __restrict__ vh, const u16* __restrict__ rproj,
    const float* __restrict__ u_bias, const float* __restrict__ v_bias,
    u16* __restrict__ ao)
{
    __shared__ u16 K_s[64 * 64];
    __shared__ u16 R_s[128 * 64];
    __shared__ u16 Vt_s[64][72];
    __shared__ u16 TP_s[4][16][88];

    int bh = blockIdx.x;
    int b = bh >> 3, h = bh & 7;
    int q0 = blockIdx.y * 64;
    int tid = threadIdx.x, w = tid >> 6, lane = tid & 63;
    int lr = lane & 15, lk = lane >> 4;
    int woff = 48 - 16 * w;
    int swz = (lr & 7) * 8;
    int c16 = ((lane & 7) ^ (lane >> 3)) * 8;

    s16x8 qu[2], qv[2];
    {
        int qrow = q0 + 16 * w + lr;
        const u16* qp = &qh[((b * S + qrow) * H + h) * DH];
        #pragma unroll
        for (int f = 0; f < 2; ++f) {
            int d0 = lk * 8 + f * 32;
            s16x8 qraw = *(const s16x8*)&qp[d0];
            s16x8 xu, xv;
            #pragma unroll
            for (int j = 0; j < 8; ++j) {
                float qf = bf2f((u16)qraw[j]);
                xu[j] = (short)f2bf((qf + u_bias[h * DH + d0 + j]) * 0.125f);
                xv[j] = (short)f2bf((qf + v_bias[h * DH + d0 + j]) * 0.125f);
            }
            qu[f] = xu; qv[f] = xv;
        }
    }

    float l_part[4] = {0.f, 0.f, 0.f, 0.f};
    f32x4 opv[4] = {};

    for (int kt = 0; kt < 8; ++kt) {
        int k0 = kt * 64;
        int rbase = k0 - q0 + 448;

        #pragma unroll
        for (int l = 0; l < 2; ++l) {
            int chunk = w * 2 + l;
            int r = chunk * 8 + (lane >> 3);
            GLOAD16(&kh[((b * S + k0 + r) * H + h) * DH + c16], &K_s[chunk * 512]);
        }
        #pragma unroll
        for (int l = 0; l < 4; ++l) {
            int chunk = w * 4 + l;
            int jr = chunk * 8 + (lane >> 3);
            int rr = rbase + jr; if (rr > 1022) rr = 1022;
            GLOAD16(&rproj[rr * D + h * DH + c16], &R_s[chunk * 512]);
        }
        {
            int kk2 = (tid & 31) * 2;
            int n8  = (tid >> 5) * 8;
            const u16* vp = &vh[((b * S + k0 + kk2) * H + h) * DH + n8];
            s16x8 v0 = *(const s16x8*)vp;
            s16x8 v1 = *(const s16x8*)(vp + H * DH);
            #pragma unroll
            for (int e = 0; e < 8; ++e) {
                ushort2 pr; pr.x = (u16)v0[e]; pr.y = (u16)v1[e];
                *(ushort2*)&Vt_s[n8 + e][kk2] = pr;
            }
        }
        __syncthreads();

        f32x4 sacc[4] = {};
        #pragma unroll
        for (int ks = 0; ks < 2; ++ks) {
            s16x8 bfr[4];
            #pragma unroll
            for (int cf = 0; cf < 4; ++cf)
                bfr[cf] = *(const s16x8*)&K_s[(cf * 16 + lr) * 64 + ((ks * 32 + lk * 8) ^ swz)];
            #pragma unroll
            for (int cf = 0; cf < 4; ++cf)
                sacc[cf] = __builtin_amdgcn_mfma_f32_16x16x32_bf16(
                    qu[ks], bfr[cf], sacc[cf], 0, 0, 0);
        }
        f32x4 tacc[5] = {};
        #pragma unroll
        for (int ks = 0; ks < 2; ++ks) {
            #pragma unroll
            for (int cf = 0; cf < 5; ++cf) {
                s16x8 bfr = *(const s16x8*)&R_s[(woff + cf * 16 + lr) * 64 + ((ks * 32 + lk * 8) ^ swz)];
                tacc[cf] = __builtin_amdgcn_mfma_f32_16x16x32_bf16(
                    qv[ks], bfr, tacc[cf], 0, 0, 0);
            }
        }
        #pragma unroll
        for (int cf = 0; cf < 5; ++cf)
            #pragma unroll
            for (int r = 0; r < 4; ++r)
                TP_s[w][lk * 4 + r][cf * 16 + lr] = f2bf(tacc[cf][r]);
        asm volatile("s_waitcnt lgkmcnt(0)" ::: "memory");

        #pragma unroll
        for (int cf = 0; cf < 4; ++cf)
            #pragma unroll
            for (int r = 0; r < 4; ++r) {
                int ql = lk * 4 + r, kk = lr + cf * 16;
                float p = __expf(sacc[cf][r] + bf2f(TP_s[w][ql][kk - ql + 15]));
                l_part[r] += p;
                TP_s[w][ql][kk] = f2bf(p);
            }
        asm volatile("s_waitcnt lgkmcnt(0)" ::: "memory");

        #pragma unroll
        for (int ks = 0; ks < 2; ++ks) {
            s16x8 pa = *(const s16x8*)&TP_s[w][lr][ks * 32 + lk * 8];
            #pragma unroll
            for (int cf = 0; cf < 4; ++cf) {
                s16x8 vf = *(const s16x8*)&Vt_s[cf * 16 + lr][ks * 32 + lk * 8];
                opv[cf] = __builtin_amdgcn_mfma_f32_16x16x32_bf16(
                    pa, vf, opv[cf], 0, 0, 0);
            }
        }
        __syncthreads();
    }

    #pragma unroll
    for (int mask = 1; mask < 16; mask <<= 1)
        #pragma unroll
        for (int r = 0; r < 4; ++r)
            l_part[r] += __shfl_xor(l_part[r], mask, 64);

    #pragma unroll
    for (int cf = 0; cf < 4; ++cf)
        #pragma unroll
        for (int r = 0; r < 4; ++r) {
            int qrow = q0 + 16 * w + lk * 4 + r;
            ao[((b * S + qrow) * H + h) * DH + lr + 16 * cf] =
                f2bf(opv[cf][r] / l_part[r]);
        }
}

// ---------------------------------------------------------------------------
extern "C" void kernel_launch(void* const* d_in, const int* in_sizes, int n_in,
                              void* d_out, int out_size, void* d_ws, size_t ws_size,
                              hipStream_t stream) {
    const float* q       = (const float*)d_in[0];
    const float* k       = (const float*)d_in[1];
    const float* v       = (const float*)d_in[2];
    const float* pos_emb = (const float*)d_in[3];
    const float* Wq = (const float*)d_in[4];  const float* bq = (const float*)d_in[5];
    const float* Wk = (const float*)d_in[6];  const float* bk = (const float*)d_in[7];
    const float* Wv = (const float*)d_in[8];  const float* bv = (const float*)d_in[9];
    const float* Wr = (const float*)d_in[10]; const float* br = (const float*)d_in[11];
    const float* Wo = (const float*)d_in[12]; const float* bo = (const float*)d_in[13];
    const float* u_bias = (const float*)d_in[14];
    const float* v_bias = (const float*)d_in[15];
    const float* ln_g = (const float*)d_in[16];
    const float* ln_b = (const float*)d_in[17];

    float* out = (float*)d_out;
    u16* ws = (u16*)d_ws;

    const int NBS = B * S * D;        // 2097152
    const int NW  = D * D;            // 262144
    const int NPE = 1024 * 512;       // padded pe/rproj (row 1023 zero)

    u16* pe_b  = ws;
    u16* qb    = pe_b + NPE;
    u16* kb    = qb + NBS;
    u16* vb    = kb + NBS;
    u16* Wqb   = vb + NBS;
    u16* Wkb   = Wqb + NW;
    u16* Wvb   = Wkb + NW;
    u16* Wrb   = Wvb + NW;
    u16* Wob   = Wrb + NW;
    u16* rproj = Wob + NW;
    u16* qhb   = rproj + NPE;
    u16* khb   = qhb + NBS;
    u16* vhb   = khb + NBS;
    u16* aob   = vhb + NBS;
    int* ctr   = (int*)(aob + NBS);   // 32 stripe counters

    dim3 blk(256);

    prep<<<2048, blk, 0, stream>>>(pos_emb, q, k, v, Wq, Wk, Wv, Wr, Wo,
                                   pe_b, qb, kb, vb, Wqb, Wkb, Wvb, Wrb, Wob, ctr);

    proj_qkvr<<<dim3(4, 32, 4), blk, 0, stream>>>(
        qb, kb, vb, pe_b, Wqb, Wkb, Wvb, Wrb, bq, bk, bv, br,
        qhb, khb, vhb, rproj);

    attn_mfma<<<dim3(B * H, S / 64), blk, 0, stream>>>(qhb, khb, vhb, rproj,
                                                       u_bias, v_bias, aob);

    proj_out_ln<<<dim3(4, 32), blk, 0, stream>>>(aob, Wob, bo, q, out,
                                                 ln_g, ln_b, ctr);
}

// Round 19
// 79.887 us; speedup vs baseline: 2.9919x; 1.3992x over previous
//
#include <hip/hip_runtime.h>
#include <math.h>

#define B 8
#define S 512
#define D 512
#define H 8
#define DH 64
#define VOCAB (2 * (S - 1) + 1)   // 1023
#define GK 512
// Best verified configuration (r14, 80.07us). History:
// r13 measurement: proj LDS bank conflicts 2e8 -> r14 XOR swizzle (-5us).
// r15 cast-fusion +6.5us; r16/r17 coop grid.sync +240us; r18 atomic-fence
// LN fusion +31us -> all cross-kernel fusion mechanisms cost more than the
// ~8us/boundary they remove on 8-XCD. attn staging/occupancy/pipeline levers
// all null (r9/r11/r12); only serial-softmax removal helped (r10, -5us).

typedef unsigned short u16;
typedef __attribute__((ext_vector_type(8))) short s16x8;
typedef __attribute__((ext_vector_type(4))) float f32x4;

__device__ __forceinline__ u16 f2bf(float f) {
    union { float f; unsigned u; } a; a.f = f;
    unsigned r = a.u + 0x7FFF + ((a.u >> 16) & 1);
    return (u16)(r >> 16);
}
__device__ __forceinline__ float bf2f(u16 h) {
    union { unsigned u; float f; } a; a.u = ((unsigned)h) << 16;
    return a.f;
}
__device__ __forceinline__ void cvt8(const float* __restrict__ s, u16* __restrict__ d) {
    float4 a = *(const float4*)s;
    float4 b = *(const float4*)(s + 4);
    s16x8 o;
    o[0] = f2bf(a.x); o[1] = f2bf(a.y); o[2] = f2bf(a.z); o[3] = f2bf(a.w);
    o[4] = f2bf(b.x); o[5] = f2bf(b.y); o[6] = f2bf(b.z); o[7] = f2bf(b.w);
    *(s16x8*)d = o;
}

#define GLOAD16(gp, lp) __builtin_amdgcn_global_load_lds( \
    (const __attribute__((address_space(1))) unsigned int*)(gp), \
    (__attribute__((address_space(3))) unsigned int*)(lp), 16, 0, 0)

// ---------------------------------------------------------------------------
// Fused prep: pe-table recovery + 5 weight casts + q/k/v casts (verified r6).
// ---------------------------------------------------------------------------
__global__ __launch_bounds__(256) void prep(
    const float* __restrict__ pos_emb,
    const float* __restrict__ q, const float* __restrict__ k, const float* __restrict__ v,
    const float* __restrict__ Wq, const float* __restrict__ Wk, const float* __restrict__ Wv,
    const float* __restrict__ Wr, const float* __restrict__ Wo,
    u16* __restrict__ pe_b, u16* __restrict__ qb, u16* __restrict__ kb, u16* __restrict__ vb,
    u16* __restrict__ Wqb, u16* __restrict__ Wkb, u16* __restrict__ Wvb,
    u16* __restrict__ Wrb, u16* __restrict__ Wob)
{
    const int NPE8 = (1024 * 512) / 8;   // 65536
    const int NW8  = (512 * 512) / 8;    // 32768
    const int NBS8 = (B * S * D) / 8;    // 262144
    const int total = NPE8 + 5 * NW8 + 3 * NBS8;
    for (int i = blockIdx.x * 256 + threadIdx.x; i < total; i += gridDim.x * 256) {
        if (i < NPE8) {
            int e = i * 8;
            int row = e >> 9, col = e & 511;
            if (row >= VOCAB) {
                *(s16x8*)&pe_b[e] = (s16x8)(short)0;
            } else {
                int qq = (row < S) ? (S - 1) : 0;
                int kk = (row < S) ? row : (row - (S - 1));
                cvt8(&pos_emb[(qq * S + kk) * D + col], &pe_b[e]);
            }
            continue;
        }
        int j = i - NPE8;
        if (j < 5 * NW8) {
            int wi = j >> 15;
            int e = (j & (NW8 - 1)) * 8;
            const float* src; u16* dst;
            if      (wi == 0) { src = Wq; dst = Wqb; }
            else if (wi == 1) { src = Wk; dst = Wkb; }
            else if (wi == 2) { src = Wv; dst = Wvb; }
            else if (wi == 3) { src = Wr; dst = Wrb; }
            else              { src = Wo; dst = Wob; }
            cvt8(&src[e], &dst[e]);
            continue;
        }
        int j2 = j - 5 * NW8;
        int qi = j2 >> 18;
        int e = (j2 & (NBS8 - 1)) * 8;
        const float* src; u16* dst;
        if      (qi == 0) { src = q; dst = qb; }
        else if (qi == 1) { src = k; dst = kb; }
        else              { src = v; dst = vb; }
        cvt8(&src[e], &dst[e]);
    }
}

// ---------------------------------------------------------------------------
// 128x128-tile bf16 MFMA GEMM with both-sides XOR swizzle (r14-verified):
// staging source 16B-slot = (lane&7)^(lane>>3); LDS linear; fragment read
// col ^= (lr&7)*8. Conflict-free (r13 PMC: 2e8 -> ~0).
// ---------------------------------------------------------------------------
template<bool F32OUT>
__device__ __forceinline__ void gemm128_body(
    const u16* __restrict__ A, const u16* __restrict__ W,
    const float* __restrict__ bias, const float* __restrict__ resid,
    u16* __restrict__ Cb, float* __restrict__ Cf,
    int m0, int n0, u16* As, u16* Ws)
{
    int tid = threadIdx.x;
    int w = tid >> 6, lane = tid & 63;
    int wr = w >> 1, wc = w & 1;
    int lr = lane & 15, lk = lane >> 4;
    int c16 = ((lane & 7) ^ (lane >> 3)) * 8;    // swizzled source col (u16)
    int swz = (lr & 7) * 8;                      // read-side XOR (u16)
    f32x4 acc[4][4] = {};

    for (int k0 = 0; k0 < GK; k0 += 64) {
        #pragma unroll
        for (int l = 0; l < 4; ++l) {
            int chunk = w * 4 + l;
            int r = chunk * 8 + (lane >> 3);
            GLOAD16(&A[(m0 + r) * GK + k0 + c16], &As[chunk * 512]);
            GLOAD16(&W[(n0 + r) * GK + k0 + c16], &Ws[chunk * 512]);
        }
        __syncthreads();
        #pragma unroll
        for (int ks = 0; ks < 2; ++ks) {
            s16x8 fa[4], fb[4];
            #pragma unroll
            for (int f = 0; f < 4; ++f) {
                fa[f] = *(const s16x8*)&As[(wr * 64 + f * 16 + lr) * 64 + ((ks * 32 + lk * 8) ^ swz)];
                fb[f] = *(const s16x8*)&Ws[(wc * 64 + f * 16 + lr) * 64 + ((ks * 32 + lk * 8) ^ swz)];
            }
            #pragma unroll
            for (int fm = 0; fm < 4; ++fm)
                #pragma unroll
                for (int fn = 0; fn < 4; ++fn)
                    acc[fm][fn] = __builtin_amdgcn_mfma_f32_16x16x32_bf16(
                        fa[fm], fb[fn], acc[fm][fn], 0, 0, 0);
        }
        __syncthreads();
    }
    #pragma unroll
    for (int fm = 0; fm < 4; ++fm) {
        #pragma unroll
        for (int r = 0; r < 4; ++r) {
            int m = m0 + wr * 64 + fm * 16 + lk * 4 + r;
            #pragma unroll
            for (int fn = 0; fn < 4; ++fn) {
                int n = n0 + wc * 64 + fn * 16 + lr;
                float vv = acc[fm][fn][r] + bias[n];
                if (F32OUT) Cf[m * 512 + n] = vv + resid[m * 512 + n];
                else        Cb[m * 512 + n] = f2bf(vv);
            }
        }
    }
}

__global__ __launch_bounds__(256) void proj_qkvr(
    const u16* __restrict__ qb, const u16* __restrict__ kb, const u16* __restrict__ vb,
    const u16* __restrict__ pe_b,
    const u16* __restrict__ Wqb, const u16* __restrict__ Wkb, const u16* __restrict__ Wvb,
    const u16* __restrict__ Wrb,
    const float* __restrict__ bq, const float* __restrict__ bk, const float* __restrict__ bv,
    const float* __restrict__ br,
    u16* __restrict__ qhb, u16* __restrict__ khb, u16* __restrict__ vhb,
    u16* __restrict__ rproj)
{
    __shared__ u16 As[128 * 64];
    __shared__ u16 Ws[128 * 64];
    const u16 *A, *W; const float* bias; u16* C;
    int z = blockIdx.z;
    if      (z == 0) { A = qb;   W = Wqb; bias = bq; C = qhb; }
    else if (z == 1) { A = kb;   W = Wkb; bias = bk; C = khb; }
    else if (z == 2) { A = vb;   W = Wvb; bias = bv; C = vhb; }
    else             { A = pe_b; W = Wrb; bias = br; C = rproj;
                       if (blockIdx.y >= 8) return; }   // pe: M=1024
    gemm128_body<false>(A, W, bias, nullptr, C, nullptr,
                        blockIdx.y * 128, blockIdx.x * 128, As, Ws);
}

__global__ __launch_bounds__(256) void proj_out(
    const u16* __restrict__ aob, const u16* __restrict__ Wob,
    const float* __restrict__ bo, const float* __restrict__ resid,
    float* __restrict__ out)
{
    __shared__ u16 As[128 * 64];
    __shared__ u16 Ws[128 * 64];
    gemm128_body<true>(aob, Wob, bo, resid, nullptr, out,
                       blockIdx.y * 128, blockIdx.x * 128, As, Ws);
}

// ---------------------------------------------------------------------------
// Fused relative attention — r10/r14-verified structure (single-buffer,
// gload+swizzle K/R, reg-staged V, max-free softmax, one end reduce).
// ---------------------------------------------------------------------------
__global__ __launch_bounds__(256, 2) void attn_mfma(
    const u16* __restrict__ qh, const u16* __restrict__ kh,
    const u16* __restrict__ vh, const u16* __restrict__ rproj,
    const float* __restrict__ u_bias, const float* __restrict__ v_bias,
    u16* __restrict__ ao)
{
    __shared__ u16 K_s[64 * 64];
    __shared__ u16 R_s[128 * 64];
    __shared__ u16 Vt_s[64][72];
    __shared__ u16 TP_s[4][16][88];

    int bh = blockIdx.x;
    int b = bh >> 3, h = bh & 7;
    int q0 = blockIdx.y * 64;
    int tid = threadIdx.x, w = tid >> 6, lane = tid & 63;
    int lr = lane & 15, lk = lane >> 4;
    int woff = 48 - 16 * w;
    int swz = (lr & 7) * 8;
    int c16 = ((lane & 7) ^ (lane >> 3)) * 8;

    s16x8 qu[2], qv[2];
    {
        int qrow = q0 + 16 * w + lr;
        const u16* qp = &qh[((b * S + qrow) * H + h) * DH];
        #pragma unroll
        for (int f = 0; f < 2; ++f) {
            int d0 = lk * 8 + f * 32;
            s16x8 qraw = *(const s16x8*)&qp[d0];
            s16x8 xu, xv;
            #pragma unroll
            for (int j = 0; j < 8; ++j) {
                float qf = bf2f((u16)qraw[j]);
                xu[j] = (short)f2bf((qf + u_bias[h * DH + d0 + j]) * 0.125f);
                xv[j] = (short)f2bf((qf + v_bias[h * DH + d0 + j]) * 0.125f);
            }
            qu[f] = xu; qv[f] = xv;
        }
    }

    float l_part[4] = {0.f, 0.f, 0.f, 0.f};
    f32x4 opv[4] = {};

    for (int kt = 0; kt < 8; ++kt) {
        int k0 = kt * 64;
        int rbase = k0 - q0 + 448;

        #pragma unroll
        for (int l = 0; l < 2; ++l) {
            int chunk = w * 2 + l;
            int r = chunk * 8 + (lane >> 3);
            GLOAD16(&kh[((b * S + k0 + r) * H + h) * DH + c16], &K_s[chunk * 512]);
        }
        #pragma unroll
        for (int l = 0; l < 4; ++l) {
            int chunk = w * 4 + l;
            int jr = chunk * 8 + (lane >> 3);
            int rr = rbase + jr; if (rr > 1022) rr = 1022;
            GLOAD16(&rproj[rr * D + h * DH + c16], &R_s[chunk * 512]);
        }
        {
            int kk2 = (tid & 31) * 2;
            int n8  = (tid >> 5) * 8;
            const u16* vp = &vh[((b * S + k0 + kk2) * H + h) * DH + n8];
            s16x8 v0 = *(const s16x8*)vp;
            s16x8 v1 = *(const s16x8*)(vp + H * DH);
            #pragma unroll
            for (int e = 0; e < 8; ++e) {
                ushort2 pr; pr.x = (u16)v0[e]; pr.y = (u16)v1[e];
                *(ushort2*)&Vt_s[n8 + e][kk2] = pr;
            }
        }
        __syncthreads();

        f32x4 sacc[4] = {};
        #pragma unroll
        for (int ks = 0; ks < 2; ++ks) {
            s16x8 bfr[4];
            #pragma unroll
            for (int cf = 0; cf < 4; ++cf)
                bfr[cf] = *(const s16x8*)&K_s[(cf * 16 + lr) * 64 + ((ks * 32 + lk * 8) ^ swz)];
            #pragma unroll
            for (int cf = 0; cf < 4; ++cf)
                sacc[cf] = __builtin_amdgcn_mfma_f32_16x16x32_bf16(
                    qu[ks], bfr[cf], sacc[cf], 0, 0, 0);
        }
        f32x4 tacc[5] = {};
        #pragma unroll
        for (int ks = 0; ks < 2; ++ks) {
            #pragma unroll
            for (int cf = 0; cf < 5; ++cf) {
                s16x8 bfr = *(const s16x8*)&R_s[(woff + cf * 16 + lr) * 64 + ((ks * 32 + lk * 8) ^ swz)];
                tacc[cf] = __builtin_amdgcn_mfma_f32_16x16x32_bf16(
                    qv[ks], bfr, tacc[cf], 0, 0, 0);
            }
        }
        #pragma unroll
        for (int cf = 0; cf < 5; ++cf)
            #pragma unroll
            for (int r = 0; r < 4; ++r)
                TP_s[w][lk * 4 + r][cf * 16 + lr] = f2bf(tacc[cf][r]);
        asm volatile("s_waitcnt lgkmcnt(0)" ::: "memory");

        #pragma unroll
        for (int cf = 0; cf < 4; ++cf)
            #pragma unroll
            for (int r = 0; r < 4; ++r) {
                int ql = lk * 4 + r, kk = lr + cf * 16;
                float p = __expf(sacc[cf][r] + bf2f(TP_s[w][ql][kk - ql + 15]));
                l_part[r] += p;
                TP_s[w][ql][kk] = f2bf(p);
            }
        asm volatile("s_waitcnt lgkmcnt(0)" ::: "memory");

        #pragma unroll
        for (int ks = 0; ks < 2; ++ks) {
            s16x8 pa = *(const s16x8*)&TP_s[w][lr][ks * 32 + lk * 8];
            #pragma unroll
            for (int cf = 0; cf < 4; ++cf) {
                s16x8 vf = *(const s16x8*)&Vt_s[cf * 16 + lr][ks * 32 + lk * 8];
                opv[cf] = __builtin_amdgcn_mfma_f32_16x16x32_bf16(
                    pa, vf, opv[cf], 0, 0, 0);
            }
        }
        __syncthreads();
    }

    #pragma unroll
    for (int mask = 1; mask < 16; mask <<= 1)
        #pragma unroll
        for (int r = 0; r < 4; ++r)
            l_part[r] += __shfl_xor(l_part[r], mask, 64);

    #pragma unroll
    for (int cf = 0; cf < 4; ++cf)
        #pragma unroll
        for (int r = 0; r < 4; ++r) {
            int qrow = q0 + 16 * w + lk * 4 + r;
            ao[((b * S + qrow) * H + h) * DH + lr + 16 * cf] =
                f2bf(opv[cf][r] / l_part[r]);
        }
}

// ---------------------------------------------------------------------------
// In-place LayerNorm over last dim (D=512). One wave per row.
// ---------------------------------------------------------------------------
__global__ __launch_bounds__(256) void ln_kernel(
    float* __restrict__ out, const float* __restrict__ g, const float* __restrict__ bta)
{
    int row = blockIdx.x * 4 + threadIdx.x / 64;
    int lane = threadIdx.x % 64;
    float vals[8];
    float sum = 0.f;
    #pragma unroll
    for (int j = 0; j < 8; ++j) {
        vals[j] = out[row * D + lane + j * 64];
        sum += vals[j];
    }
    #pragma unroll
    for (int off = 32; off; off >>= 1) sum += __shfl_xor(sum, off, 64);
    float mu = sum / (float)D;
    float sq = 0.f;
    #pragma unroll
    for (int j = 0; j < 8; ++j) { float dv = vals[j] - mu; sq += dv * dv; }
    #pragma unroll
    for (int off = 32; off; off >>= 1) sq += __shfl_xor(sq, off, 64);
    float rstd = rsqrtf(sq / (float)D + 1e-5f);
    #pragma unroll
    for (int j = 0; j < 8; ++j) {
        int c = lane + j * 64;
        out[row * D + c] = (vals[j] - mu) * rstd * g[c] + bta[c];
    }
}

// ---------------------------------------------------------------------------
extern "C" void kernel_launch(void* const* d_in, const int* in_sizes, int n_in,
                              void* d_out, int out_size, void* d_ws, size_t ws_size,
                              hipStream_t stream) {
    const float* q       = (const float*)d_in[0];
    const float* k       = (const float*)d_in[1];
    const float* v       = (const float*)d_in[2];
    const float* pos_emb = (const float*)d_in[3];
    const float* Wq = (const float*)d_in[4];  const float* bq = (const float*)d_in[5];
    const float* Wk = (const float*)d_in[6];  const float* bk = (const float*)d_in[7];
    const float* Wv = (const float*)d_in[8];  const float* bv = (const float*)d_in[9];
    const float* Wr = (const float*)d_in[10]; const float* br = (const float*)d_in[11];
    const float* Wo = (const float*)d_in[12]; const float* bo = (const float*)d_in[13];
    const float* u_bias = (const float*)d_in[14];
    const float* v_bias = (const float*)d_in[15];
    const float* ln_g = (const float*)d_in[16];
    const float* ln_b = (const float*)d_in[17];

    float* out = (float*)d_out;
    u16* ws = (u16*)d_ws;

    const int NBS = B * S * D;        // 2097152
    const int NW  = D * D;            // 262144
    const int NPE = 1024 * 512;       // padded pe/rproj (row 1023 zero)

    u16* pe_b  = ws;
    u16* qb    = pe_b + NPE;
    u16* kb    = qb + NBS;
    u16* vb    = kb + NBS;
    u16* Wqb   = vb + NBS;
    u16* Wkb   = Wqb + NW;
    u16* Wvb   = Wkb + NW;
    u16* Wrb   = Wvb + NW;
    u16* Wob   = Wrb + NW;
    u16* rproj = Wob + NW;
    u16* qhb   = rproj + NPE;
    u16* khb   = qhb + NBS;
    u16* vhb   = khb + NBS;
    u16* aob   = vhb + NBS;

    dim3 blk(256);

    prep<<<2048, blk, 0, stream>>>(pos_emb, q, k, v, Wq, Wk, Wv, Wr, Wo,
                                   pe_b, qb, kb, vb, Wqb, Wkb, Wvb, Wrb, Wob);

    proj_qkvr<<<dim3(4, 32, 4), blk, 0, stream>>>(
        qb, kb, vb, pe_b, Wqb, Wkb, Wvb, Wrb, bq, bk, bv, br,
        qhb, khb, vhb, rproj);

    attn_mfma<<<dim3(B * H, S / 64), blk, 0, stream>>>(qhb, khb, vhb, rproj,
                                                       u_bias, v_bias, aob);

    proj_out<<<dim3(4, 32), blk, 0, stream>>>(aob, Wob, bo, q, out);

    ln_kernel<<<B * S / 4, blk, 0, stream>>>(out, ln_g, ln_b);
}